// Round 6
// baseline (394.845 us; speedup 1.0000x reference)
//
#include <hip/hip_runtime.h>

#define NN 100000
#define NE 1600000
#define C 32
#define TILE 2048
#define NSCB ((NN + TILE - 1) / TILE)   // 49 scan blocks

#define SHIFT 8
#define BINW 256                         // nodes per bin
#define NBIN ((NN + BINW - 1) / BINW)    // 391
#define NGRP 8                           // sub-regions per bin (~XCDs)
#define EPB 4096                         // edges per block in binning kernels
#define NBLK ((NE + EPB - 1) / EPB)      // 391

// ---------------- kernels ----------------

__global__ void k_zero(int* __restrict__ cnt, int* __restrict__ cntg) {
    int i = blockIdx.x * blockDim.x + threadIdx.x;
    if (i < NN) cnt[i] = 0;
    if (i < NBIN * NGRP) cntg[i] = 0;
}

// node in-degree histogram + (bin,group) histogram. Block b owns edge
// window [b*EPB,(b+1)*EPB), group g = b&7 — identical mapping in k_bin.
__global__ __launch_bounds__(256) void k_hist2(const int* __restrict__ ei,
                                               int* __restrict__ cnt,
                                               int* __restrict__ cntg) {
    __shared__ int lh[NBIN];
    for (int i = threadIdx.x; i < NBIN; i += 256) lh[i] = 0;
    __syncthreads();
    int b = blockIdx.x, g = b & (NGRP - 1);
    int e0 = b * EPB, e1 = min(e0 + EPB, NE);
    for (int e = e0 + threadIdx.x; e < e1; e += 256) {
        int cl = ei[NE + e];
        atomicAdd(&cnt[cl], 1);
        atomicAdd(&lh[cl >> SHIFT], 1);
    }
    __syncthreads();
    for (int i = threadIdx.x; i < NBIN; i += 256) {
        int v = lh[i];
        if (v) atomicAdd(&cntg[i * NGRP + g], v);
    }
}

// phase 1: per-tile sums of cnt (coalesced)
__global__ __launch_bounds__(256) void k_psum(const int* __restrict__ cnt,
                                              int* __restrict__ bsum) {
    int base = blockIdx.x * TILE;
    int s = 0;
    for (int i = threadIdx.x; i < TILE; i += 256) {
        int idx = base + i;
        if (idx < NN) s += cnt[idx];
    }
#pragma unroll
    for (int d = 32; d; d >>= 1) s += __shfl_down(s, d);
    __shared__ int wsum[4];
    if ((threadIdx.x & 63) == 0) wsum[threadIdx.x >> 6] = s;
    __syncthreads();
    if (threadIdx.x == 0) bsum[blockIdx.x] = wsum[0] + wsum[1] + wsum[2] + wsum[3];
}

// phase 2: one wave scans the 49 tile sums -> exclusive tile offsets
__global__ __launch_bounds__(64) void k_bscan(const int* __restrict__ bsum,
                                              int* __restrict__ boff) {
    int t = threadIdx.x;
    int orig = (t < NSCB) ? bsum[t] : 0;
    int v = orig;
#pragma unroll
    for (int d = 1; d < 64; d <<= 1) {
        int u = __shfl_up(v, d);
        if (t >= d) v += u;
    }
    if (t < NSCB) boff[t] = v - orig;  // exclusive
}

// phase 3: per-tile exclusive scan -> off, dinv
__global__ __launch_bounds__(256) void k_fin(const int* __restrict__ cnt,
                                             const int* __restrict__ boff,
                                             int* __restrict__ off,
                                             float* __restrict__ dinv) {
    __shared__ int ts[256];
    int t = threadIdx.x;
    int s0 = blockIdx.x * TILE + t * 8;
    int v[8];
    int sum = 0;
#pragma unroll
    for (int k = 0; k < 8; ++k) {
        int idx = s0 + k;
        v[k] = (idx < NN) ? cnt[idx] : 0;
        sum += v[k];
    }
    ts[t] = sum;
    __syncthreads();
    for (int d = 1; d < 256; d <<= 1) {
        int u = (t >= d) ? ts[t - d] : 0;
        __syncthreads();
        ts[t] += u;
        __syncthreads();
    }
    int run = boff[blockIdx.x] + ts[t] - sum;
#pragma unroll
    for (int k = 0; k < 8; ++k) {
        int idx = s0 + k;
        if (idx < NN) {
            off[idx] = run;
            dinv[idx] = rsqrtf(1.0f + (float)v[k]);  // deg incl. self-loop
        }
        run += v[k];
        if (idx == NN - 1) off[NN] = run;  // == NE
    }
}

// (bin,group) start cursors from off + cntg prefix
__global__ __launch_bounds__(256) void k_gscan(const int* __restrict__ off,
                                               const int* __restrict__ cntg,
                                               int* __restrict__ gcur) {
    int bin = blockIdx.x * blockDim.x + threadIdx.x;
    if (bin < NBIN) {
        int run = off[bin << SHIFT];
#pragma unroll
        for (int g = 0; g < NGRP; ++g) {
            gcur[bin * NGRP + g] = run;
            run += cntg[bin * NGRP + g];
        }
    }
}

// pass 1: scatter packed (src<<8 | col&255) into (bin,group) sub-regions.
// Frontier lines are (bin,group)-exclusive -> fill before eviction.
__global__ __launch_bounds__(256) void k_bin(const int* __restrict__ ei,
                                             int* __restrict__ gcur,
                                             int* __restrict__ tmp) {
    int b = blockIdx.x, g = b & (NGRP - 1);
    int e0 = b * EPB, e1 = min(e0 + EPB, NE);
    for (int e = e0 + threadIdx.x; e < e1; e += 256) {
        int src = ei[e], cl = ei[NE + e];
        int pos = atomicAdd(&gcur[(cl >> SHIFT) * NGRP + g], 1);
        tmp[pos] = (src << SHIFT) | (cl & (BINW - 1));
    }
}

// pass 2: one block per bin; exact placement via LDS cursors; srt window
// (~16KB) stays hot in this block's L2.
__global__ __launch_bounds__(256) void k_place(const int* __restrict__ off,
                                               const int* __restrict__ tmp,
                                               int* __restrict__ srt) {
    __shared__ int lcur[BINW];
    int bin = blockIdx.x;
    int nb = bin << SHIFT;
    int nend = min(nb + BINW, NN);
    for (int i = threadIdx.x; i < nend - nb; i += 256) lcur[i] = off[nb + i];
    __syncthreads();
    int s0 = off[nb], s1 = off[nend];
    for (int i = s0 + threadIdx.x; i < s1; i += 256) {
        int v = tmp[i];
        int pos = atomicAdd(&lcur[v & (BINW - 1)], 1);
        srt[pos] = v >> SHIFT;
    }
}

// h = x @ W^T  (into ws)
__global__ void k_linear(const float* __restrict__ x,
                         const float* __restrict__ W,
                         float* __restrict__ h) {
    __shared__ float Ws[C][C + 1];
    __shared__ float xs[8][C];
    int t = threadIdx.x;
    for (int i = t; i < C * C; i += 256)
        Ws[i / C][i % C] = W[i];

    int node0 = blockIdx.x * 8;
    int lnode = t >> 5;
    int cout  = t & 31;
    int node  = node0 + lnode;
    {
        int idx = node0 * C + t;
        xs[lnode][cout] = (idx < NN * C) ? x[idx] : 0.0f;
    }
    __syncthreads();
    if (node < NN) {
        float s = 0.0f;
#pragma unroll
        for (int k = 0; k < C; ++k) s += xs[lnode][k] * Ws[cout][k];
        h[node * C + cout] = s;
    }
}

// one 64-lane wave per node: segmented sum over bucketed edges, 2x unrolled
// (4 h-rows in flight per wave), + bias + self-loop, coalesced row store.
__global__ __launch_bounds__(256) void k_agg(const int* __restrict__ off,
                                             const int* __restrict__ srt,
                                             const float* __restrict__ h,
                                             const float* __restrict__ dinv,
                                             const float* __restrict__ b,
                                             float* __restrict__ out) {
    int n = (blockIdx.x * blockDim.x + threadIdx.x) >> 6;
    if (n >= NN) return;
    int lane = threadIdx.x & 63;
    int c = lane & 31, p = lane >> 5;
    int beg = off[n], end = off[n + 1];
    float s = 0.0f, s2 = 0.0f;
    int j = beg + p;
    for (; j + 2 < end; j += 4) {
        int r0 = srt[j], r1 = srt[j + 2];
        float d0 = dinv[r0], d1 = dinv[r1];
        s  += h[r0 * C + c] * d0;
        s2 += h[r1 * C + c] * d1;
    }
    for (; j < end; j += 2) {
        int r = srt[j];
        s += h[r * C + c] * dinv[r];
    }
    s += s2;
    s += __shfl_xor(s, 32);
    if (p == 0) {
        float dn = dinv[n];
        out[n * C + c] = b[c] + dn * (s + dn * h[n * C + c]);
    }
}

// ---------------- launch ----------------

extern "C" void kernel_launch(void* const* d_in, const int* in_sizes, int n_in,
                              void* d_out, int out_size, void* d_ws, size_t ws_size,
                              hipStream_t stream) {
    const float* x  = (const float*)d_in[0];
    const int*   ei = (const int*)d_in[1];
    const float* W  = (const float*)d_in[2];
    const float* b  = (const float*)d_in[3];
    float* out = (float*)d_out;

    // workspace (~20.5 MB). tmp (6.4MB) overlays h (12.8MB): tmp is dead
    // before k_linear writes h (strict stream order).
    char* ws = (char*)d_ws;
    size_t o = 0;
    float* h    = (float*)(ws + o);
    int*   tmp  = (int*)(ws + o);   o += (size_t)NN * C * 4;        o = (o + 255) & ~(size_t)255;
    int*   cnt  = (int*)(ws + o);   o += (size_t)NN * 4;            o = (o + 255) & ~(size_t)255;
    int*   off  = (int*)(ws + o);   o += (size_t)(NN + 1) * 4;      o = (o + 255) & ~(size_t)255;
    float* dinv = (float*)(ws + o); o += (size_t)NN * 4;            o = (o + 255) & ~(size_t)255;
    int*   srt  = (int*)(ws + o);   o += (size_t)NE * 4;            o = (o + 255) & ~(size_t)255;
    int*   bsum = (int*)(ws + o);   o += (size_t)NSCB * 4;          o = (o + 255) & ~(size_t)255;
    int*   boff = (int*)(ws + o);   o += (size_t)NSCB * 4;          o = (o + 255) & ~(size_t)255;
    int*   cntg = (int*)(ws + o);   o += (size_t)NBIN * NGRP * 4;   o = (o + 255) & ~(size_t)255;
    int*   gcur = (int*)(ws + o);

    k_zero<<<(NN + 255) / 256, 256, 0, stream>>>(cnt, cntg);
    k_hist2<<<NBLK, 256, 0, stream>>>(ei, cnt, cntg);
    k_psum<<<NSCB, 256, 0, stream>>>(cnt, bsum);
    k_bscan<<<1, 64, 0, stream>>>(bsum, boff);
    k_fin<<<NSCB, 256, 0, stream>>>(cnt, boff, off, dinv);
    k_gscan<<<(NBIN + 255) / 256, 256, 0, stream>>>(off, cntg, gcur);
    k_bin<<<NBLK, 256, 0, stream>>>(ei, gcur, tmp);
    k_place<<<NBIN, 256, 0, stream>>>(off, tmp, srt);
    k_linear<<<(NN + 7) / 8, 256, 0, stream>>>(x, W, h);
    k_agg<<<(NN * 64 + 255) / 256, 256, 0, stream>>>(off, srt, h, dinv, b, out);
}

// Round 7
// 263.155 us; speedup vs baseline: 1.5004x; 1.5004x over previous
//
#include <hip/hip_runtime.h>

#define NN 100000
#define NE 1600000
#define C 32
#define TILE 2048
#define NSCB ((NN + TILE - 1) / TILE)        // 49 node-scan tiles

#define SHIFT 8
#define BINW 256                              // nodes per bin
#define NBIN ((NN + BINW - 1) / BINW)         // 391
#define EPB2 8192                             // edges per block (binning)
#define NBLK2 ((NE + EPB2 - 1) / EPB2)        // 196
#define VTOT (NBIN * NBLK2)                   // 76636 (bin-major cmat scan)
#define VTILE 2048
#define NVT ((VTOT + VTILE - 1) / VTILE)      // 38

// ---------------- kernels ----------------

__global__ void k_zero(int* __restrict__ cnt) {
    int i = blockIdx.x * blockDim.x + threadIdx.x;
    if (i < NN) cnt[i] = 0;
}

// fused: global node-degree hist + per-block coarse-bin hist (LDS, no
// global cursor atomics). cmat written block-major = coalesced.
__global__ __launch_bounds__(256) void k_histA(const int* __restrict__ ei,
                                               int* __restrict__ cnt,
                                               int* __restrict__ cmat) {
    __shared__ int lh[NBIN];
    for (int i = threadIdx.x; i < NBIN; i += 256) lh[i] = 0;
    __syncthreads();
    int b = blockIdx.x;
    int e0 = b * EPB2, e1 = min(e0 + EPB2, NE);
    for (int e = e0 + threadIdx.x; e < e1; e += 256) {
        int cl = ei[NE + e];
        atomicAdd(&cnt[cl], 1);
        atomicAdd(&lh[cl >> SHIFT], 1);
    }
    __syncthreads();
    for (int i = threadIdx.x; i < NBIN; i += 256)
        cmat[b * NBIN + i] = lh[i];
}

// ---- node-degree scan (off, dinv): 3-phase, unchanged machinery ----

__global__ __launch_bounds__(256) void k_psum(const int* __restrict__ cnt,
                                              int* __restrict__ bsum) {
    int base = blockIdx.x * TILE;
    int s = 0;
    for (int i = threadIdx.x; i < TILE; i += 256) {
        int idx = base + i;
        if (idx < NN) s += cnt[idx];
    }
#pragma unroll
    for (int d = 32; d; d >>= 1) s += __shfl_down(s, d);
    __shared__ int wsum[4];
    if ((threadIdx.x & 63) == 0) wsum[threadIdx.x >> 6] = s;
    __syncthreads();
    if (threadIdx.x == 0) bsum[blockIdx.x] = wsum[0] + wsum[1] + wsum[2] + wsum[3];
}

// one wave scans n (<=64) tile sums -> exclusive offsets
__global__ __launch_bounds__(64) void k_bscan(const int* __restrict__ bsum,
                                              int* __restrict__ boff, int n) {
    int t = threadIdx.x;
    int orig = (t < n) ? bsum[t] : 0;
    int v = orig;
#pragma unroll
    for (int d = 1; d < 64; d <<= 1) {
        int u = __shfl_up(v, d);
        if (t >= d) v += u;
    }
    if (t < n) boff[t] = v - orig;  // exclusive
}

__global__ __launch_bounds__(256) void k_fin(const int* __restrict__ cnt,
                                             const int* __restrict__ boff,
                                             int* __restrict__ off,
                                             float* __restrict__ dinv) {
    __shared__ int ts[256];
    int t = threadIdx.x;
    int s0 = blockIdx.x * TILE + t * 8;
    int v[8];
    int sum = 0;
#pragma unroll
    for (int k = 0; k < 8; ++k) {
        int idx = s0 + k;
        v[k] = (idx < NN) ? cnt[idx] : 0;
        sum += v[k];
    }
    ts[t] = sum;
    __syncthreads();
    for (int d = 1; d < 256; d <<= 1) {
        int u = (t >= d) ? ts[t - d] : 0;
        __syncthreads();
        ts[t] += u;
        __syncthreads();
    }
    int run = boff[blockIdx.x] + ts[t] - sum;
#pragma unroll
    for (int k = 0; k < 8; ++k) {
        int idx = s0 + k;
        if (idx < NN) {
            off[idx] = run;
            dinv[idx] = rsqrtf(1.0f + (float)v[k]);  // deg incl. self-loop
        }
        run += v[k];
        if (idx == NN - 1) off[NN] = run;  // == NE
    }
}

// ---- cmat scan (bin-major virtual order) -> gbase ----

__global__ __launch_bounds__(256) void k_psumC(const int* __restrict__ cmat,
                                               int* __restrict__ bsum2) {
    int base = blockIdx.x * VTILE;
    int s = 0;
    for (int i = threadIdx.x; i < VTILE; i += 256) {
        int v = base + i;
        if (v < VTOT) {
            int bin = v / NBLK2, blk = v - bin * NBLK2;
            s += cmat[blk * NBIN + bin];
        }
    }
#pragma unroll
    for (int d = 32; d; d >>= 1) s += __shfl_down(s, d);
    __shared__ int wsum[4];
    if ((threadIdx.x & 63) == 0) wsum[threadIdx.x >> 6] = s;
    __syncthreads();
    if (threadIdx.x == 0) bsum2[blockIdx.x] = wsum[0] + wsum[1] + wsum[2] + wsum[3];
}

__global__ __launch_bounds__(256) void k_finC(const int* __restrict__ cmat,
                                              const int* __restrict__ boff2,
                                              int* __restrict__ gbase) {
    __shared__ int ts[256];
    int t = threadIdx.x;
    int s0 = blockIdx.x * VTILE + t * 8;
    int v[8];
    int sum = 0;
#pragma unroll
    for (int k = 0; k < 8; ++k) {
        int idx = s0 + k;
        if (idx < VTOT) {
            int bin = idx / NBLK2, blk = idx - bin * NBLK2;
            v[k] = cmat[blk * NBIN + bin];
        } else v[k] = 0;
        sum += v[k];
    }
    ts[t] = sum;
    __syncthreads();
    for (int d = 1; d < 256; d <<= 1) {
        int u = (t >= d) ? ts[t - d] : 0;
        __syncthreads();
        ts[t] += u;
        __syncthreads();
    }
    int run = boff2[blockIdx.x] + ts[t] - sum;
#pragma unroll
    for (int k = 0; k < 8; ++k) {
        int idx = s0 + k;
        if (idx < VTOT) gbase[idx] = run;   // bin-major, coalesced write
        run += v[k];
    }
}

// deterministic scatter into coarse bins: LDS cursors seeded from gbase.
// Zero global atomics; per-block per-bin segments are contiguous and
// adjacent across blocks -> lines fill.
__global__ __launch_bounds__(256) void k_binD(const int* __restrict__ ei,
                                              const int* __restrict__ gbase,
                                              int* __restrict__ tmp) {
    __shared__ int lcur[NBIN];
    int b = blockIdx.x;
    for (int i = threadIdx.x; i < NBIN; i += 256)
        lcur[i] = gbase[i * NBLK2 + b];
    __syncthreads();
    int e0 = b * EPB2, e1 = min(e0 + EPB2, NE);
    for (int e = e0 + threadIdx.x; e < e1; e += 256) {
        int src = ei[e], cl = ei[NE + e];
        int pos = atomicAdd(&lcur[cl >> SHIFT], 1);   // LDS atomic: cheap
        tmp[pos] = (src << SHIFT) | (cl & (BINW - 1));
    }
}

// one block per bin: exact CSR placement via LDS cursors
__global__ __launch_bounds__(256) void k_place(const int* __restrict__ off,
                                               const int* __restrict__ tmp,
                                               int* __restrict__ srt) {
    __shared__ int lcur[BINW];
    int bin = blockIdx.x;
    int nb = bin << SHIFT;
    int nend = min(nb + BINW, NN);
    for (int i = threadIdx.x; i < nend - nb; i += 256) lcur[i] = off[nb + i];
    __syncthreads();
    int s0 = off[nb], s1 = off[nend];
    for (int i = s0 + threadIdx.x; i < s1; i += 256) {
        int v = tmp[i];
        int pos = atomicAdd(&lcur[v & (BINW - 1)], 1);
        srt[pos] = v >> SHIFT;
    }
}

// h = x @ W^T  (into ws)
__global__ void k_linear(const float* __restrict__ x,
                         const float* __restrict__ W,
                         float* __restrict__ h) {
    __shared__ float Ws[C][C + 1];
    __shared__ float xs[8][C];
    int t = threadIdx.x;
    for (int i = t; i < C * C; i += 256)
        Ws[i / C][i % C] = W[i];

    int node0 = blockIdx.x * 8;
    int lnode = t >> 5;
    int cout  = t & 31;
    int node  = node0 + lnode;
    {
        int idx = node0 * C + t;
        xs[lnode][cout] = (idx < NN * C) ? x[idx] : 0.0f;
    }
    __syncthreads();
    if (node < NN) {
        float s = 0.0f;
#pragma unroll
        for (int k = 0; k < C; ++k) s += xs[lnode][k] * Ws[cout][k];
        h[node * C + cout] = s;
    }
}

// one 64-lane wave per node: segmented sum over bucketed edges, 2x unrolled,
// + bias + self-loop, coalesced row store. No atomics.
__global__ __launch_bounds__(256) void k_agg(const int* __restrict__ off,
                                             const int* __restrict__ srt,
                                             const float* __restrict__ h,
                                             const float* __restrict__ dinv,
                                             const float* __restrict__ b,
                                             float* __restrict__ out) {
    int n = (blockIdx.x * blockDim.x + threadIdx.x) >> 6;
    if (n >= NN) return;
    int lane = threadIdx.x & 63;
    int c = lane & 31, p = lane >> 5;
    int beg = off[n], end = off[n + 1];
    float s = 0.0f, s2 = 0.0f;
    int j = beg + p;
    for (; j + 2 < end; j += 4) {
        int r0 = srt[j], r1 = srt[j + 2];
        float d0 = dinv[r0], d1 = dinv[r1];
        s  += h[r0 * C + c] * d0;
        s2 += h[r1 * C + c] * d1;
    }
    for (; j < end; j += 2) {
        int r = srt[j];
        s += h[r * C + c] * dinv[r];
    }
    s += s2;
    s += __shfl_xor(s, 32);
    if (p == 0) {
        float dn = dinv[n];
        out[n * C + c] = b[c] + dn * (s + dn * h[n * C + c]);
    }
}

// ---------------- launch ----------------

extern "C" void kernel_launch(void* const* d_in, const int* in_sizes, int n_in,
                              void* d_out, int out_size, void* d_ws, size_t ws_size,
                              hipStream_t stream) {
    const float* x  = (const float*)d_in[0];
    const int*   ei = (const int*)d_in[1];
    const float* W  = (const float*)d_in[2];
    const float* b  = (const float*)d_in[3];
    float* out = (float*)d_out;

    // ws (~20.4 MB). tmp/cmat/gbase overlay h's 12.8MB (all dead before
    // k_linear writes h; strict stream order).
    char* ws = (char*)d_ws;
    size_t o = 0;
    float* h    = (float*)(ws + o);
    int*   tmp  = (int*)(ws + o);
    int*   cmat = (int*)(ws + o + ((size_t)NE * 4 + 256));            // after tmp
    int*   gbase= (int*)(ws + o + ((size_t)NE * 4 + 256) + ((size_t)VTOT * 4 + 256));
    o += (size_t)NN * C * 4;        o = (o + 255) & ~(size_t)255;
    int*   cnt  = (int*)(ws + o);   o += (size_t)NN * 4;              o = (o + 255) & ~(size_t)255;
    int*   off  = (int*)(ws + o);   o += (size_t)(NN + 1) * 4;        o = (o + 255) & ~(size_t)255;
    float* dinv = (float*)(ws + o); o += (size_t)NN * 4;              o = (o + 255) & ~(size_t)255;
    int*   srt  = (int*)(ws + o);   o += (size_t)NE * 4;              o = (o + 255) & ~(size_t)255;
    int*   bsum = (int*)(ws + o);   o += (size_t)NSCB * 4;            o = (o + 255) & ~(size_t)255;
    int*   boff = (int*)(ws + o);   o += (size_t)NSCB * 4;            o = (o + 255) & ~(size_t)255;
    int*   bsum2= (int*)(ws + o);   o += (size_t)NVT * 4;             o = (o + 255) & ~(size_t)255;
    int*   boff2= (int*)(ws + o);

    k_zero<<<(NN + 255) / 256, 256, 0, stream>>>(cnt);
    k_histA<<<NBLK2, 256, 0, stream>>>(ei, cnt, cmat);
    k_psum<<<NSCB, 256, 0, stream>>>(cnt, bsum);
    k_bscan<<<1, 64, 0, stream>>>(bsum, boff, NSCB);
    k_fin<<<NSCB, 256, 0, stream>>>(cnt, boff, off, dinv);
    k_psumC<<<NVT, 256, 0, stream>>>(cmat, bsum2);
    k_bscan<<<1, 64, 0, stream>>>(bsum2, boff2, NVT);
    k_finC<<<NVT, 256, 0, stream>>>(cmat, boff2, gbase);
    k_binD<<<NBLK2, 256, 0, stream>>>(ei, gbase, tmp);
    k_place<<<NBIN, 256, 0, stream>>>(off, tmp, srt);
    k_linear<<<(NN + 7) / 8, 256, 0, stream>>>(x, W, h);
    k_agg<<<(NN * 64 + 255) / 256, 256, 0, stream>>>(off, srt, h, dinv, b, out);
}

// Round 8
// 197.993 us; speedup vs baseline: 1.9942x; 1.3291x over previous
//
#include <hip/hip_runtime.h>

#define NN 100000
#define NE 1600000
#define C 32

#define SHIFT 8
#define BINW 256                              // nodes per bin
#define NBIN ((NN + BINW - 1) / BINW)         // 391
#define EPB2 8192                             // edges per block (binning)
#define NBLK2 ((NE + EPB2 - 1) / EPB2)        // 196
#define VTOT (NBIN * NBLK2)                   // 76636 (bin-major cmat scan)
#define VTILE 2048
#define NVT ((VTOT + VTILE - 1) / VTILE)      // 38

// ---------------- kernels ----------------

// per-block coarse-bin histogram (LDS only; no global atomics)
__global__ __launch_bounds__(256) void k_histB(const int* __restrict__ ei,
                                               int* __restrict__ cmat) {
    __shared__ int lh[NBIN];
    for (int i = threadIdx.x; i < NBIN; i += 256) lh[i] = 0;
    __syncthreads();
    int b = blockIdx.x;
    int e0 = b * EPB2, e1 = min(e0 + EPB2, NE);
    for (int e = e0 + threadIdx.x; e < e1; e += 256)
        atomicAdd(&lh[ei[NE + e] >> SHIFT], 1);
    __syncthreads();
    for (int i = threadIdx.x; i < NBIN; i += 256)
        cmat[b * NBIN + i] = lh[i];
}

// ---- cmat scan (bin-major virtual order) -> gbase ----

__global__ __launch_bounds__(256) void k_psumC(const int* __restrict__ cmat,
                                               int* __restrict__ bsum2) {
    int base = blockIdx.x * VTILE;
    int s = 0;
    for (int i = threadIdx.x; i < VTILE; i += 256) {
        int v = base + i;
        if (v < VTOT) {
            int bin = v / NBLK2, blk = v - bin * NBLK2;
            s += cmat[blk * NBIN + bin];
        }
    }
#pragma unroll
    for (int d = 32; d; d >>= 1) s += __shfl_down(s, d);
    __shared__ int wsum[4];
    if ((threadIdx.x & 63) == 0) wsum[threadIdx.x >> 6] = s;
    __syncthreads();
    if (threadIdx.x == 0) bsum2[blockIdx.x] = wsum[0] + wsum[1] + wsum[2] + wsum[3];
}

// one wave scans n (<=64) tile sums -> exclusive offsets
__global__ __launch_bounds__(64) void k_bscan(const int* __restrict__ bsum,
                                              int* __restrict__ boff, int n) {
    int t = threadIdx.x;
    int orig = (t < n) ? bsum[t] : 0;
    int v = orig;
#pragma unroll
    for (int d = 1; d < 64; d <<= 1) {
        int u = __shfl_up(v, d);
        if (t >= d) v += u;
    }
    if (t < n) boff[t] = v - orig;  // exclusive
}

__global__ __launch_bounds__(256) void k_finC(const int* __restrict__ cmat,
                                              const int* __restrict__ boff2,
                                              int* __restrict__ gbase) {
    __shared__ int ts[256];
    int t = threadIdx.x;
    int s0 = blockIdx.x * VTILE + t * 8;
    int v[8];
    int sum = 0;
#pragma unroll
    for (int k = 0; k < 8; ++k) {
        int idx = s0 + k;
        if (idx < VTOT) {
            int bin = idx / NBLK2, blk = idx - bin * NBLK2;
            v[k] = cmat[blk * NBIN + bin];
        } else v[k] = 0;
        sum += v[k];
    }
    ts[t] = sum;
    __syncthreads();
    for (int d = 1; d < 256; d <<= 1) {
        int u = (t >= d) ? ts[t - d] : 0;
        __syncthreads();
        ts[t] += u;
        __syncthreads();
    }
    int run = boff2[blockIdx.x] + ts[t] - sum;
#pragma unroll
    for (int k = 0; k < 8; ++k) {
        int idx = s0 + k;
        if (idx < VTOT) gbase[idx] = run;   // bin-major, coalesced
        run += v[k];
    }
}

// deterministic scatter into coarse bins (LDS cursors from gbase)
__global__ __launch_bounds__(256) void k_binD(const int* __restrict__ ei,
                                              const int* __restrict__ gbase,
                                              int* __restrict__ tmp) {
    __shared__ int lcur[NBIN];
    int b = blockIdx.x;
    for (int i = threadIdx.x; i < NBIN; i += 256)
        lcur[i] = gbase[i * NBLK2 + b];
    __syncthreads();
    int e0 = b * EPB2, e1 = min(e0 + EPB2, NE);
    for (int e = e0 + threadIdx.x; e < e1; e += 256) {
        int src = ei[e], cl = ei[NE + e];
        int pos = atomicAdd(&lcur[cl >> SHIFT], 1);   // LDS atomic: cheap
        tmp[pos] = (src << SHIFT) | (cl & (BINW - 1));
    }
}

// one block per bin: LDS node-histogram of the bin slice -> off/dinv,
// then exact CSR placement. Zero global atomics anywhere.
__global__ __launch_bounds__(256) void k_placeB(const int* __restrict__ gbase,
                                                const int* __restrict__ tmp,
                                                int* __restrict__ srt,
                                                int* __restrict__ off,
                                                float* __restrict__ dinv) {
    __shared__ int lcnt[BINW];
    __shared__ int ts[BINW];
    __shared__ int lcur[BINW];
    int bin = blockIdx.x, t = threadIdx.x;
    int s0 = gbase[bin * NBLK2];
    int s1 = (bin + 1 < NBIN) ? gbase[(bin + 1) * NBLK2] : NE;
    lcnt[t] = 0;
    __syncthreads();
    for (int i = s0 + t; i < s1; i += 256)
        atomicAdd(&lcnt[tmp[i] & (BINW - 1)], 1);
    __syncthreads();
    int cv = lcnt[t];
    ts[t] = cv;
    __syncthreads();
    for (int d = 1; d < 256; d <<= 1) {   // Hillis-Steele inclusive
        int u = (t >= d) ? ts[t - d] : 0;
        __syncthreads();
        ts[t] += u;
        __syncthreads();
    }
    int base = s0 + ts[t] - cv;           // exclusive node offset
    lcur[t] = base;
    int node = (bin << SHIFT) + t;
    if (node < NN) {
        off[node] = base;
        dinv[node] = rsqrtf(1.0f + (float)cv);   // deg incl. self-loop
        if (node == NN - 1) off[NN] = NE;
    }
    __syncthreads();
    for (int i = s0 + t; i < s1; i += 256) {
        int v = tmp[i];
        int pos = atomicAdd(&lcur[v & (BINW - 1)], 1);
        srt[pos] = v >> SHIFT;
    }
}

// h' = dinv * (x @ W^T)  — pre-scaled so k_agg needs no dinv[src] gather
__global__ void k_linear(const float* __restrict__ x,
                         const float* __restrict__ W,
                         const float* __restrict__ dinv,
                         float* __restrict__ h) {
    __shared__ float Ws[C][C + 1];
    __shared__ float xs[8][C];
    int t = threadIdx.x;
    for (int i = t; i < C * C; i += 256)
        Ws[i / C][i % C] = W[i];

    int node0 = blockIdx.x * 8;
    int lnode = t >> 5;
    int cout  = t & 31;
    int node  = node0 + lnode;
    {
        int idx = node0 * C + t;
        xs[lnode][cout] = (idx < NN * C) ? x[idx] : 0.0f;
    }
    __syncthreads();
    if (node < NN) {
        float s = 0.0f;
#pragma unroll
        for (int k = 0; k < C; ++k) s += xs[lnode][k] * Ws[cout][k];
        h[node * C + cout] = dinv[node] * s;
    }
}

// one 64-lane wave per node: out = b + dn*(sum_r h'[r] + h'[n])
__global__ __launch_bounds__(256) void k_agg(const int* __restrict__ off,
                                             const int* __restrict__ srt,
                                             const float* __restrict__ h,
                                             const float* __restrict__ dinv,
                                             const float* __restrict__ b,
                                             float* __restrict__ out) {
    int n = (blockIdx.x * blockDim.x + threadIdx.x) >> 6;
    if (n >= NN) return;
    int lane = threadIdx.x & 63;
    int c = lane & 31, p = lane >> 5;
    int beg = off[n], end = off[n + 1];
    float s = 0.0f, s2 = 0.0f;
    int j = beg + p;
    for (; j + 2 < end; j += 4) {
        int r0 = srt[j], r1 = srt[j + 2];
        s  += h[r0 * C + c];
        s2 += h[r1 * C + c];
    }
    for (; j < end; j += 2) s += h[srt[j] * C + c];
    s += s2;
    s += __shfl_xor(s, 32);
    if (p == 0) {
        float dn = dinv[n];
        out[n * C + c] = b[c] + dn * (s + h[n * C + c]);
    }
}

// ---------------- launch ----------------

extern "C" void kernel_launch(void* const* d_in, const int* in_sizes, int n_in,
                              void* d_out, int out_size, void* d_ws, size_t ws_size,
                              hipStream_t stream) {
    const float* x  = (const float*)d_in[0];
    const int*   ei = (const int*)d_in[1];
    const float* W  = (const float*)d_in[2];
    const float* b  = (const float*)d_in[3];
    float* out = (float*)d_out;

    // ws (~20 MB). tmp/cmat/gbase overlay h's 12.8MB region (all dead
    // before k_linear writes h; strict stream order).
    char* ws = (char*)d_ws;
    size_t o = 0;
    float* h    = (float*)(ws + o);
    int*   tmp  = (int*)(ws + o);
    int*   cmat = (int*)(ws + o + ((size_t)NE * 4 + 256));
    int*   gbase= (int*)(ws + o + ((size_t)NE * 4 + 256) + ((size_t)VTOT * 4 + 256));
    o += (size_t)NN * C * 4;        o = (o + 255) & ~(size_t)255;
    int*   off  = (int*)(ws + o);   o += (size_t)(NN + 1) * 4;        o = (o + 255) & ~(size_t)255;
    float* dinv = (float*)(ws + o); o += (size_t)NN * 4;              o = (o + 255) & ~(size_t)255;
    int*   srt  = (int*)(ws + o);   o += (size_t)NE * 4;              o = (o + 255) & ~(size_t)255;
    int*   bsum2= (int*)(ws + o);   o += (size_t)NVT * 4;             o = (o + 255) & ~(size_t)255;
    int*   boff2= (int*)(ws + o);

    k_histB<<<NBLK2, 256, 0, stream>>>(ei, cmat);
    k_psumC<<<NVT, 256, 0, stream>>>(cmat, bsum2);
    k_bscan<<<1, 64, 0, stream>>>(bsum2, boff2, NVT);
    k_finC<<<NVT, 256, 0, stream>>>(cmat, boff2, gbase);
    k_binD<<<NBLK2, 256, 0, stream>>>(ei, gbase, tmp);
    k_placeB<<<NBIN, 256, 0, stream>>>(gbase, tmp, srt, off, dinv);
    k_linear<<<(NN + 7) / 8, 256, 0, stream>>>(x, W, dinv, h);
    k_agg<<<(NN * 64 + 255) / 256, 256, 0, stream>>>(off, srt, h, dinv, b, out);
}